// Round 6
// baseline (202.787 us; speedup 1.0000x reference)
//
#include <hip/hip_runtime.h>

// Problem constants
#define HW 4096           // H*W
#define CHW 262144        // C*H*W
#define OUT_ELEMS 4194304 // B*C*H*W
#define FLT_BIG 3.4e38f
#define LSTR 136          // Bs row stride in shorts (16B-aligned rows, 2-way bank alias = free)

typedef __attribute__((ext_vector_type(8))) short  short8;   // MFMA A/B frag (4 VGPR)
typedef __attribute__((ext_vector_type(4))) float  floatx4;  // MFMA C/D frag
typedef __attribute__((ext_vector_type(4))) int    intx4;

// ws layout:
//   [0,2048)        hist u32[512]
//   [2048,2056)     sse double
//   [2056,2060)     done u32
//   [4096,6144)     enorm f32[512]
//   [8192,139264)   planes_e u16[512][128]  ([eh(64)|el(64)] per code)

__device__ __forceinline__ unsigned bf16_rne(float f) {
    unsigned u = __float_as_uint(f);
    return (u + 0x7FFFu + ((u >> 16) & 1u)) >> 16;  // RNE bf16 bits
}

__device__ __forceinline__ void split8(const float* f, intx4* hi, intx4* lo) {
    unsigned h[4], l[4];
#pragma unroll
    for (int j = 0; j < 4; ++j) {
        const unsigned h0 = bf16_rne(f[2 * j]);
        const unsigned h1 = bf16_rne(f[2 * j + 1]);
        const float hf0 = __uint_as_float(h0 << 16);
        const float hf1 = __uint_as_float(h1 << 16);
        const unsigned l0 = bf16_rne(f[2 * j] - hf0);
        const unsigned l1 = bf16_rne(f[2 * j + 1] - hf1);
        h[j] = h0 | (h1 << 16);
        l[j] = l0 | (l1 << 16);
    }
    *hi = intx4{(int)h[0], (int)h[1], (int)h[2], (int)h[3]};
    *lo = intx4{(int)l[0], (int)l[1], (int)l[2], (int)l[3]};
}

// prep: 16 blocks x 256 threads; 32 codes/block.
// Converts emb -> [eh|el] planes (coalesced both sides) + exact fp32 enorm.
__global__ void vq_prep(const float* __restrict__ emb,
                        unsigned short* __restrict__ planes_e,
                        float* __restrict__ enorm) {
    const int t = threadIdx.x;
    const int lane = t & 63;
#pragma unroll
    for (int i = 0; i < 8; ++i) {
        const int f    = (i << 8) + t;
        const int code = (blockIdx.x << 5) + (f >> 6);  // wave-uniform
        const float v  = emb[(code << 6) + lane];       // 256B coalesced
        const unsigned h = bf16_rne(v);
        const float hf   = __uint_as_float(h << 16);
        const unsigned l = bf16_rne(v - hf);
        planes_e[(code << 7) + lane]      = (unsigned short)h;
        planes_e[(code << 7) + 64 + lane] = (unsigned short)l;
        float s = v * v;
#pragma unroll
        for (int off = 32; off > 0; off >>= 1) s += __shfl_xor(s, off, 64);
        if (lane == 0) enorm[code] = s;
    }
}

// Main: 1024 blocks x 256 threads; 64 rows/block (one (b,h) stripe, row = w).
// Wave wv: rows [32*(wv>>1), +32), code-half (wv&1) of each 64-code chunk.
// A-frags (split-bf16 of x) live in registers for all 8 chunks; B double-buffered.
// NOTE (R5 bug): waves sharing rows but owning different code-halves must merge
// through DISTINCT LDS slots [half][row]; phase 3 merges the two halves.
__global__ __launch_bounds__(256, 4)
void vq_main(const float* __restrict__ x_in, const float* __restrict__ emb,
             const unsigned short* __restrict__ planes_e,
             const float* __restrict__ enorm, const float* __restrict__ weight,
             float* __restrict__ out, float* __restrict__ idx_out,
             unsigned* __restrict__ hist, double* __restrict__ sse_acc,
             unsigned* __restrict__ done, float* __restrict__ scal) {
    __shared__ short  Bs0[64 * LSTR];  // 17.4 KB
    __shared__ short  Bs1[64 * LSTR];  // 17.4 KB
    __shared__ float  b1s[2][64], b2s[2][64];
    __shared__ int    i1s[2][64], i2s[2][64], qidx[64];
    __shared__ double ls_red[4];
    __shared__ int    ls_ired[4];
    __shared__ int    ls_flag;

    const int t     = threadIdx.x;
    const int lane  = t & 63;
    const int wv    = t >> 6;
    const int col   = lane & 15;
    const int quad  = lane >> 4;
    const int blk   = blockIdx.x;
    const int mrow0 = (wv >> 1) << 5;   // wave row base (0/32)
    const int khalf = wv & 1;           // code-half within each chunk
    const int ncol0 = khalf << 5;       // code base within chunk (0/32)
    const int b = blk >> 6, h = blk & 63;
    const float* xb = x_in + (size_t)b * CHW + h * 64;

    // ---- B chunk load/store macros (fully coalesced global; 16B LDS pieces) ----
    const char* pe = (const char*)planes_e;
    intx4 pf0, pf1, pf2, pf3;
#define LOADCHUNK(nc) { const char* p = pe + (nc) * 16384 + t * 16;              \
        pf0 = *(const intx4*)(p);          pf1 = *(const intx4*)(p + 4096);      \
        pf2 = *(const intx4*)(p + 8192);   pf3 = *(const intx4*)(p + 12288); }
#define WRITECHUNK(dst) { const int n0 = (t >> 4), k0 = (t & 15) << 3;           \
        *(intx4*)&dst[(n0     ) * LSTR + k0] = pf0;                              \
        *(intx4*)&dst[(n0 + 16) * LSTR + k0] = pf1;                              \
        *(intx4*)&dst[(n0 + 32) * LSTR + k0] = pf2;                              \
        *(intx4*)&dst[(n0 + 48) * LSTR + k0] = pf3; }

    LOADCHUNK(0);  // chunk-0 loads in flight during A conversion

    // ---- A-frags: 16 x-values per Mt, direct from BCHW global (coalesced),
    // split to bf16 hi/lo, held in VGPRs for the whole kernel ----
    short8 Ah[2][2], Al[2][2];
#pragma unroll
    for (int m = 0; m < 2; ++m) {
        const int w = mrow0 + (m << 4) + col;
#pragma unroll
        for (int u = 0; u < 2; ++u) {
            float f[8];
#pragma unroll
            for (int j = 0; j < 8; ++j) {
                const int c = (u << 5) + (quad << 3) + j;
                f[j] = xb[(size_t)c * HW + w];   // lanes: 16 consecutive w -> 4 lines/instr
            }
            intx4 hi, lo;
            split8(f, &hi, &lo);
            Ah[m][u] = __builtin_bit_cast(short8, hi);
            Al[m][u] = __builtin_bit_cast(short8, lo);
        }
    }

    WRITECHUNK(Bs0);
    __syncthreads();

    float B1[8], B2[8]; int I1[8], I2[8];
#pragma unroll
    for (int s = 0; s < 8; ++s) { B1[s] = FLT_BIG; B2[s] = FLT_BIG; I1[s] = 0x3FFFFFFF; I2[s] = 0x3FFFFFFF; }

    short* bcur = Bs0;
    short* bnxt = Bs1;
    const int kBoff[6] = {0, 32, 64, 96, 0, 32};  // eh0,eh1,el0,el1,eh0,eh1 (+8*quad)

    for (int nc = 0; nc < 8; ++nc) {
        const int K0 = nc << 6;
        if (nc < 7) LOADCHUNK(nc + 1);  // prefetch overlaps MFMA phase
        const float en0 = enorm[K0 + ncol0 + col];        // issued early
        const float en1 = enorm[K0 + ncol0 + 16 + col];

        floatx4 a00{0.f,0.f,0.f,0.f}, a01{0.f,0.f,0.f,0.f};
        floatx4 a10{0.f,0.f,0.f,0.f}, a11{0.f,0.f,0.f,0.f};
        const short* brow0 = bcur + (ncol0 + col) * LSTR + (quad << 3);
        const short* brow1 = brow0 + 16 * LSTR;
#pragma unroll
        for (int kt = 0; kt < 6; ++kt) {
            const short8 bv0 = *(const short8*)(brow0 + kBoff[kt]);
            const short8 bv1 = *(const short8*)(brow1 + kBoff[kt]);
            const int u = kt & 1;
            const short8 am0 = (kt < 4) ? Ah[0][u] : Al[0][u];
            const short8 am1 = (kt < 4) ? Ah[1][u] : Al[1][u];
            a00 = __builtin_amdgcn_mfma_f32_16x16x32_bf16(am0, bv0, a00, 0, 0, 0);
            a01 = __builtin_amdgcn_mfma_f32_16x16x32_bf16(am0, bv1, a01, 0, 0, 0);
            a10 = __builtin_amdgcn_mfma_f32_16x16x32_bf16(am1, bv0, a10, 0, 0, 0);
            a11 = __builtin_amdgcn_mfma_f32_16x16x32_bf16(am1, bv1, a11, 0, 0, 0);
        }

        // top-2 update; codes ascend per slot (nt inner, nc outer) -> strict <
        // keeps first occurrence within this wave's code subset.
#pragma unroll
        for (int nt = 0; nt < 2; ++nt) {
            const int code = K0 + ncol0 + (nt << 4) + col;
            const float en = nt ? en1 : en0;
#pragma unroll
            for (int m = 0; m < 2; ++m) {
                const floatx4 av = nt ? (m ? a11 : a01) : (m ? a10 : a00);
#pragma unroll
                for (int reg = 0; reg < 4; ++reg) {
                    const float d = fmaf(-2.f, av[reg], en);
                    const int s = (m << 2) + reg;
                    if (d < B1[s])      { B2[s] = B1[s]; I2[s] = I1[s]; B1[s] = d; I1[s] = code; }
                    else if (d < B2[s]) { B2[s] = d; I2[s] = code; }
                }
            }
        }

        if (nc < 7) WRITECHUNK(bnxt);   // idle buffer: no extra barrier needed
        __syncthreads();
        short* tmp = bcur; bcur = bnxt; bnxt = tmp;
    }

    // ---- cross-lane top-2 butterfly over col bits (disjoint code sets per
    // lane; explicit index tie-break = first-occurrence) ----
#pragma unroll
    for (int off = 1; off <= 8; off <<= 1) {
#pragma unroll
        for (int s = 0; s < 8; ++s) {
            const float ob1 = __shfl_xor(B1[s], off, 64);
            const int   oi1 = __shfl_xor(I1[s], off, 64);
            const float ob2 = __shfl_xor(B2[s], off, 64);
            const int   oi2 = __shfl_xor(I2[s], off, 64);
            if (ob1 < B1[s] || (ob1 == B1[s] && oi1 < I1[s])) {
                float nb2; int ni2;
                if (B1[s] < ob2 || (B1[s] == ob2 && I1[s] < oi2)) { nb2 = B1[s]; ni2 = I1[s]; }
                else                                              { nb2 = ob2;  ni2 = oi2; }
                B1[s] = ob1; I1[s] = oi1; B2[s] = nb2; I2[s] = ni2;
            } else if (ob1 < B2[s] || (ob1 == B2[s] && oi1 < I2[s])) {
                B2[s] = ob1; I2[s] = oi1;
            }
        }
    }
    // Publish per (code-half, row): waves 0/1 cover rows [0,32) halves 0/1,
    // waves 2/3 rows [32,64) halves 0/1 -> disjoint slots, no race (R5 fix).
    if (col == 0) {
#pragma unroll
        for (int s = 0; s < 8; ++s) {
            const int row = mrow0 + ((s >> 2) << 4) + (quad << 2) + (s & 3);
            b1s[khalf][row] = B1[s]; b2s[khalf][row] = B2[s];
            i1s[khalf][row] = I1[s]; i2s[khalf][row] = I2[s];
        }
    }
    __syncthreads();

    // ---- per-row finalize: merge the two code-half top-2 lists, fp64 rescue
    // on near-ties (exact x/emb), index out ----
    if (t < 64) {
        const int r = t;
        const float* xp = xb + r;
        float b1 = b1s[0][r], b2 = b2s[0][r];
        int   i1 = i1s[0][r], i2 = i2s[0][r];
        {   // merge half-1 candidates (top-2 of union = top-2 of merged top-2s)
            const float c1 = b1s[1][r]; const int j1 = i1s[1][r];
            const float c2 = b2s[1][r]; const int j2 = i2s[1][r];
            if (c1 < b1 || (c1 == b1 && j1 < i1))      { b2 = b1; i2 = i1; b1 = c1; i1 = j1; }
            else if (c1 < b2 || (c1 == b2 && j1 < i2)) { b2 = c1; i2 = j1; }
            if (c2 < b2 || (c2 == b2 && j2 < i2))      { b2 = c2; i2 = j2; }
        }
        if (b2 - b1 < 1e-2f) {   // split-bf16 noise ~2e-4; rescue near-ties exactly
            const float* e1p = emb + ((size_t)i1 << 6);
            const float* e2p = emb + ((size_t)i2 << 6);
            double d1 = 0.0, d2 = 0.0;
            for (int c = 0; c < 64; ++c) {
                const double xv = (double)xp[(size_t)c * HW];
                const double t1 = xv - (double)e1p[c];
                const double t2 = xv - (double)e2p[c];
                d1 = fma(t1, t1, d1);
                d2 = fma(t2, t2, d2);
            }
            if (d2 < d1 || (d2 == d1 && i2 < i1)) i1 = i2;
        }
        qidx[r] = i1;
        atomicAdd(&hist[i1], 1u);
        idx_out[(blk << 6) + r] = (float)i1;
    }
    __syncthreads();

    // ---- epilogue: quantized out (coalesced along w) + fp64 SSE ----
    {
        const int r  = lane;            // row
        const int c0 = wv << 4;         // 16 channels per wave
        const float* xp = xb + r;
        float*       op = out + (size_t)b * CHW + h * 64 + r;
        const float* eq = emb + ((size_t)qidx[r] << 6);
        double sse_local = 0.0;
#pragma unroll
        for (int cc = 0; cc < 16; ++cc) {
            const int c = c0 + cc;
            const float qc = eq[c];
            const float dx = qc - xp[(size_t)c * HW];
            sse_local += (double)dx * (double)dx;
            op[(size_t)c * HW] = qc;
        }
#pragma unroll
        for (int off = 32; off > 0; off >>= 1)
            sse_local += __shfl_down(sse_local, off, 64);
        if (lane == 0) ls_red[wv] = sse_local;
        __syncthreads();
        if (t == 0)
            atomicAdd(sse_acc, (ls_red[0] + ls_red[1]) + (ls_red[2] + ls_red[3]));
    }

    // ---- last block computes the scalars ----
    if (t == 0) {
        __threadfence();
        const unsigned old = atomicAdd(done, 1u);
        ls_flag = (old == gridDim.x - 1) ? 1 : 0;
    }
    __syncthreads();
    if (ls_flag) {
        __threadfence();
        double term = 0.0; int act = 0;
#pragma unroll
        for (int j = 0; j < 2; ++j) {
            const int k = t + (j << 8);
            const unsigned cnt = atomicAdd(&hist[k], 0u);  // coherent read
            const double p = (double)cnt / 65536.0;
            term += p * log(p + 1e-10);
            act  += (weight[k] >= 0.01f) ? 1 : 0;
        }
#pragma unroll
        for (int off = 32; off > 0; off >>= 1) {
            term += __shfl_down(term, off, 64);
            act  += __shfl_down(act,  off, 64);
        }
        if (lane == 0) { ls_red[wv] = term; ls_ired[wv] = act; }
        __syncthreads();
        if (t == 0) {
            const double s = (ls_red[0] + ls_red[1]) + (ls_red[2] + ls_red[3]);
            const int    a = ls_ired[0] + ls_ired[1] + ls_ired[2] + ls_ired[3];
            const double sse_tot = atomicAdd(sse_acc, 0.0);
            scal[0] = (float)(sse_tot / 4194304.0);  // commitment_loss
            scal[1] = (float)exp(-s);                // perplexity
            scal[2] = (float)a;                      // active_codes
        }
    }
#undef LOADCHUNK
#undef WRITECHUNK
}

extern "C" void kernel_launch(void* const* d_in, const int* in_sizes, int n_in,
                              void* d_out, int out_size, void* d_ws, size_t ws_size,
                              hipStream_t stream) {
    const float* x      = (const float*)d_in[0];  // [16,64,64,64] fp32
    const float* emb    = (const float*)d_in[1];  // [512,64] fp32
    const float* weight = (const float*)d_in[2];  // [512] fp32

    float* out = (float*)d_out;
    unsigned*       hist     = (unsigned*)d_ws;
    double*         sse      = (double*)((char*)d_ws + 2048);
    unsigned*       done     = (unsigned*)((char*)d_ws + 2056);
    float*          enorm    = (float*)((char*)d_ws + 4096);
    unsigned short* planes_e = (unsigned short*)((char*)d_ws + 8192);

    float* scal    = out + OUT_ELEMS;      // commitment, perplexity, active
    float* idx_out = out + OUT_ELEMS + 3;  // indices as float [65536]

    hipMemsetAsync(d_ws, 0, 4096, stream);  // zero hist/sse/done
    vq_prep<<<16, 256, 0, stream>>>(emb, planes_e, enorm);
    vq_main<<<1024, 256, 0, stream>>>(x, emb, planes_e, enorm, weight, out,
                                      idx_out, hist, sse, done, scal);
}

// Round 7
// 175.370 us; speedup vs baseline: 1.1563x; 1.1563x over previous
//
#include <hip/hip_runtime.h>

// Problem constants
#define HW 4096           // H*W
#define CHW 262144        // C*H*W
#define OUT_ELEMS 4194304 // B*C*H*W
#define FLT_BIG 3.4e38f
#define LSTR 136          // Bs row stride in shorts (16B-aligned rows, 2-way bank alias = free)

typedef __attribute__((ext_vector_type(8))) short  short8;   // MFMA A/B frag (4 VGPR)
typedef __attribute__((ext_vector_type(4))) float  floatx4;  // MFMA C/D frag
typedef __attribute__((ext_vector_type(4))) int    intx4;

// ws layout:
//   [0,2048)        hist u32[512]
//   [2048,2056)     sse double
//   [2056,2060)     done u32
//   [4096,6144)     enorm f32[512]
//   [8192,139264)   planes_e u16[512][128]  ([eh(64)|el(64)] per code)

__device__ __forceinline__ unsigned bf16_rne(float f) {
    unsigned u = __float_as_uint(f);
    return (u + 0x7FFFu + ((u >> 16) & 1u)) >> 16;  // RNE bf16 bits
}

__device__ __forceinline__ void split8(const float* f, intx4* hi, intx4* lo) {
    unsigned h[4], l[4];
#pragma unroll
    for (int j = 0; j < 4; ++j) {
        const unsigned h0 = bf16_rne(f[2 * j]);
        const unsigned h1 = bf16_rne(f[2 * j + 1]);
        const float hf0 = __uint_as_float(h0 << 16);
        const float hf1 = __uint_as_float(h1 << 16);
        const unsigned l0 = bf16_rne(f[2 * j] - hf0);
        const unsigned l1 = bf16_rne(f[2 * j + 1] - hf1);
        h[j] = h0 | (h1 << 16);
        l[j] = l0 | (l1 << 16);
    }
    *hi = intx4{(int)h[0], (int)h[1], (int)h[2], (int)h[3]};
    *lo = intx4{(int)l[0], (int)l[1], (int)l[2], (int)l[3]};
}

// prep: 16 blocks x 256 threads; 32 codes/block.
// Converts emb -> [eh|el] planes (coalesced both sides) + exact fp32 enorm.
// Block 0 also zeroes hist/sse/done (replaces the memset dispatch).
__global__ void vq_prep(const float* __restrict__ emb,
                        unsigned short* __restrict__ planes_e,
                        float* __restrict__ enorm,
                        unsigned* __restrict__ hist,
                        double* __restrict__ sse,
                        unsigned* __restrict__ done) {
    const int t = threadIdx.x;
    const int lane = t & 63;
    if (blockIdx.x == 0) {
        hist[t] = 0u; hist[t + 256] = 0u;
        if (t == 0) { *sse = 0.0; *done = 0u; }
    }
#pragma unroll
    for (int i = 0; i < 8; ++i) {
        const int f    = (i << 8) + t;
        const int code = (blockIdx.x << 5) + (f >> 6);  // wave-uniform
        const float v  = emb[(code << 6) + lane];       // 256B coalesced
        const unsigned h = bf16_rne(v);
        const float hf   = __uint_as_float(h << 16);
        const unsigned l = bf16_rne(v - hf);
        planes_e[(code << 7) + lane]      = (unsigned short)h;
        planes_e[(code << 7) + 64 + lane] = (unsigned short)l;
        float s = v * v;
#pragma unroll
        for (int off = 32; off > 0; off >>= 1) s += __shfl_xor(s, off, 64);
        if (lane == 0) enorm[code] = s;
    }
}

// Main: 1024 blocks x 256 threads; 64 rows/block (one (b,h) stripe, row = w).
// Wave wv: rows [32*(wv>>1), +32), code-half (wv&1) of each 64-code chunk.
// A-frags (split-bf16 of x) live in registers for all 8 chunks; B double-buffered.
// R6 lesson: NO min-occupancy demand in launch_bounds (the 128-reg combined
// VGPR+AGPR cap forced a 135-dword/thread spill -> 141 MB scratch traffic);
// and the prefetched chunk is written to LDS IMMEDIATELY (pf regs not live
// across the MFMA phase).
__global__ __launch_bounds__(256)
void vq_main(const float* __restrict__ x_in, const float* __restrict__ emb,
             const unsigned short* __restrict__ planes_e,
             const float* __restrict__ enorm, const float* __restrict__ weight,
             float* __restrict__ out, float* __restrict__ idx_out,
             unsigned* __restrict__ hist, double* __restrict__ sse_acc,
             unsigned* __restrict__ done, float* __restrict__ scal) {
    __shared__ short  Bs0[64 * LSTR];  // 17.4 KB
    __shared__ short  Bs1[64 * LSTR];  // 17.4 KB
    __shared__ float  b1s[2][64], b2s[2][64];
    __shared__ int    i1s[2][64], i2s[2][64], qidx[64];
    __shared__ double ls_red[4];
    __shared__ int    ls_ired[4];
    __shared__ int    ls_flag;

    const int t     = threadIdx.x;
    const int lane  = t & 63;
    const int wv    = t >> 6;
    const int col   = lane & 15;
    const int quad  = lane >> 4;
    const int blk   = blockIdx.x;
    const int mrow0 = (wv >> 1) << 5;   // wave row base (0/32)
    const int khalf = wv & 1;           // code-half within each chunk
    const int ncol0 = khalf << 5;       // code base within chunk (0/32)
    const int b = blk >> 6, h = blk & 63;
    const float* xb = x_in + (size_t)b * CHW + h * 64;

    // ---- B chunk stage: coalesced global load + immediate LDS write (pf regs
    // live only between the two macros -> no pressure across MFMAs) ----
    const char* pe = (const char*)planes_e;
#define STAGECHUNK(nc, dst) {                                                    \
        const char* p = pe + (nc) * 16384 + t * 16;                              \
        const intx4 pf0 = *(const intx4*)(p);                                    \
        const intx4 pf1 = *(const intx4*)(p + 4096);                             \
        const intx4 pf2 = *(const intx4*)(p + 8192);                             \
        const intx4 pf3 = *(const intx4*)(p + 12288);                            \
        const int n0 = (t >> 4), k0 = (t & 15) << 3;                             \
        *(intx4*)&dst[(n0     ) * LSTR + k0] = pf0;                              \
        *(intx4*)&dst[(n0 + 16) * LSTR + k0] = pf1;                              \
        *(intx4*)&dst[(n0 + 32) * LSTR + k0] = pf2;                              \
        *(intx4*)&dst[(n0 + 48) * LSTR + k0] = pf3; }

    STAGECHUNK(0, Bs0);

    // ---- A-frags: 16 x-values per Mt, direct from BCHW global (coalesced),
    // split to bf16 hi/lo, held in VGPRs for the whole kernel ----
    short8 Ah[2][2], Al[2][2];
#pragma unroll
    for (int m = 0; m < 2; ++m) {
        const int w = mrow0 + (m << 4) + col;
#pragma unroll
        for (int u = 0; u < 2; ++u) {
            float f[8];
#pragma unroll
            for (int j = 0; j < 8; ++j) {
                const int c = (u << 5) + (quad << 3) + j;
                f[j] = xb[(size_t)c * HW + w];   // lanes: 16 consecutive w -> 4 lines/instr
            }
            intx4 hi, lo;
            split8(f, &hi, &lo);
            Ah[m][u] = __builtin_bit_cast(short8, hi);
            Al[m][u] = __builtin_bit_cast(short8, lo);
        }
    }

    __syncthreads();

    float B1[8], B2[8]; int I1[8], I2[8];
#pragma unroll
    for (int s = 0; s < 8; ++s) { B1[s] = FLT_BIG; B2[s] = FLT_BIG; I1[s] = 0x3FFFFFFF; I2[s] = 0x3FFFFFFF; }

    short* bcur = Bs0;
    short* bnxt = Bs1;
    const int kBoff[6] = {0, 32, 64, 96, 0, 32};  // eh0,eh1,el0,el1,eh0,eh1 (+8*quad)

    for (int nc = 0; nc < 8; ++nc) {
        const int K0 = nc << 6;
        // Stage next chunk into the idle buffer NOW (it was released by the
        // previous iteration's barrier). Other waves' MFMAs hide the vmcnt wait.
        if (nc < 7) STAGECHUNK(nc + 1, bnxt);
        const float en0 = enorm[K0 + ncol0 + col];
        const float en1 = enorm[K0 + ncol0 + 16 + col];

        floatx4 a00{0.f,0.f,0.f,0.f}, a01{0.f,0.f,0.f,0.f};
        floatx4 a10{0.f,0.f,0.f,0.f}, a11{0.f,0.f,0.f,0.f};
        const short* brow0 = bcur + (ncol0 + col) * LSTR + (quad << 3);
        const short* brow1 = brow0 + 16 * LSTR;
#pragma unroll
        for (int kt = 0; kt < 6; ++kt) {
            const short8 bv0 = *(const short8*)(brow0 + kBoff[kt]);
            const short8 bv1 = *(const short8*)(brow1 + kBoff[kt]);
            const int u = kt & 1;
            const short8 am0 = (kt < 4) ? Ah[0][u] : Al[0][u];
            const short8 am1 = (kt < 4) ? Ah[1][u] : Al[1][u];
            a00 = __builtin_amdgcn_mfma_f32_16x16x32_bf16(am0, bv0, a00, 0, 0, 0);
            a01 = __builtin_amdgcn_mfma_f32_16x16x32_bf16(am0, bv1, a01, 0, 0, 0);
            a10 = __builtin_amdgcn_mfma_f32_16x16x32_bf16(am1, bv0, a10, 0, 0, 0);
            a11 = __builtin_amdgcn_mfma_f32_16x16x32_bf16(am1, bv1, a11, 0, 0, 0);
        }

        // top-2 update; codes ascend per slot (nt inner, nc outer) -> strict <
        // keeps first occurrence within this wave's code subset.
#pragma unroll
        for (int nt = 0; nt < 2; ++nt) {
            const int code = K0 + ncol0 + (nt << 4) + col;
            const float en = nt ? en1 : en0;
#pragma unroll
            for (int m = 0; m < 2; ++m) {
                const floatx4 av = nt ? (m ? a11 : a01) : (m ? a10 : a00);
#pragma unroll
                for (int reg = 0; reg < 4; ++reg) {
                    const float d = fmaf(-2.f, av[reg], en);
                    const int s = (m << 2) + reg;
                    if (d < B1[s])      { B2[s] = B1[s]; I2[s] = I1[s]; B1[s] = d; I1[s] = code; }
                    else if (d < B2[s]) { B2[s] = d; I2[s] = code; }
                }
            }
        }

        __syncthreads();
        short* tmp = bcur; bcur = bnxt; bnxt = tmp;
    }

    // ---- cross-lane top-2 butterfly over col bits (disjoint code sets per
    // lane; explicit index tie-break = first-occurrence) ----
#pragma unroll
    for (int off = 1; off <= 8; off <<= 1) {
#pragma unroll
        for (int s = 0; s < 8; ++s) {
            const float ob1 = __shfl_xor(B1[s], off, 64);
            const int   oi1 = __shfl_xor(I1[s], off, 64);
            const float ob2 = __shfl_xor(B2[s], off, 64);
            const int   oi2 = __shfl_xor(I2[s], off, 64);
            if (ob1 < B1[s] || (ob1 == B1[s] && oi1 < I1[s])) {
                float nb2; int ni2;
                if (B1[s] < ob2 || (B1[s] == ob2 && I1[s] < oi2)) { nb2 = B1[s]; ni2 = I1[s]; }
                else                                              { nb2 = ob2;  ni2 = oi2; }
                B1[s] = ob1; I1[s] = oi1; B2[s] = nb2; I2[s] = ni2;
            } else if (ob1 < B2[s] || (ob1 == B2[s] && oi1 < I2[s])) {
                B2[s] = ob1; I2[s] = oi1;
            }
        }
    }
    // Publish per (code-half, row): disjoint slots, no race (R5 fix).
    if (col == 0) {
#pragma unroll
        for (int s = 0; s < 8; ++s) {
            const int row = mrow0 + ((s >> 2) << 4) + (quad << 2) + (s & 3);
            b1s[khalf][row] = B1[s]; b2s[khalf][row] = B2[s];
            i1s[khalf][row] = I1[s]; i2s[khalf][row] = I2[s];
        }
    }
    __syncthreads();

    // ---- per-row finalize: merge the two code-half top-2 lists, fp64 rescue
    // on near-ties (exact x/emb), index out ----
    if (t < 64) {
        const int r = t;
        const float* xp = xb + r;
        float b1 = b1s[0][r], b2 = b2s[0][r];
        int   i1 = i1s[0][r], i2 = i2s[0][r];
        {   // merge half-1 candidates (top-2 of union = top-2 of merged top-2s)
            const float c1 = b1s[1][r]; const int j1 = i1s[1][r];
            const float c2 = b2s[1][r]; const int j2 = i2s[1][r];
            if (c1 < b1 || (c1 == b1 && j1 < i1))      { b2 = b1; i2 = i1; b1 = c1; i1 = j1; }
            else if (c1 < b2 || (c1 == b2 && j1 < i2)) { b2 = c1; i2 = j1; }
            if (c2 < b2 || (c2 == b2 && j2 < i2))      { b2 = c2; i2 = j2; }
        }
        if (b2 - b1 < 1e-2f) {   // split-bf16 noise ~2e-4; rescue near-ties exactly
            const float* e1p = emb + ((size_t)i1 << 6);
            const float* e2p = emb + ((size_t)i2 << 6);
            double d1 = 0.0, d2 = 0.0;
            for (int c = 0; c < 64; ++c) {
                const double xv = (double)xp[(size_t)c * HW];
                const double t1 = xv - (double)e1p[c];
                const double t2 = xv - (double)e2p[c];
                d1 = fma(t1, t1, d1);
                d2 = fma(t2, t2, d2);
            }
            if (d2 < d1 || (d2 == d1 && i2 < i1)) i1 = i2;
        }
        qidx[r] = i1;
        atomicAdd(&hist[i1], 1u);
        idx_out[(blk << 6) + r] = (float)i1;
    }
    __syncthreads();

    // ---- epilogue: quantized out (coalesced along w) + fp64 SSE ----
    {
        const int r  = lane;            // row
        const int c0 = wv << 4;         // 16 channels per wave
        const float* xp = xb + r;
        float*       op = out + (size_t)b * CHW + h * 64 + r;
        const float* eq = emb + ((size_t)qidx[r] << 6);
        double sse_local = 0.0;
#pragma unroll
        for (int cc = 0; cc < 16; ++cc) {
            const int c = c0 + cc;
            const float qc = eq[c];
            const float dx = qc - xp[(size_t)c * HW];
            sse_local += (double)dx * (double)dx;
            op[(size_t)c * HW] = qc;
        }
#pragma unroll
        for (int off = 32; off > 0; off >>= 1)
            sse_local += __shfl_down(sse_local, off, 64);
        if (lane == 0) ls_red[wv] = sse_local;
        __syncthreads();
        if (t == 0)
            atomicAdd(sse_acc, (ls_red[0] + ls_red[1]) + (ls_red[2] + ls_red[3]));
    }

    // ---- last block computes the scalars ----
    if (t == 0) {
        __threadfence();
        const unsigned old = atomicAdd(done, 1u);
        ls_flag = (old == gridDim.x - 1) ? 1 : 0;
    }
    __syncthreads();
    if (ls_flag) {
        __threadfence();
        double term = 0.0; int act = 0;
#pragma unroll
        for (int j = 0; j < 2; ++j) {
            const int k = t + (j << 8);
            const unsigned cnt = atomicAdd(&hist[k], 0u);  // coherent read
            const double p = (double)cnt / 65536.0;
            term += p * log(p + 1e-10);
            act  += (weight[k] >= 0.01f) ? 1 : 0;
        }
#pragma unroll
        for (int off = 32; off > 0; off >>= 1) {
            term += __shfl_down(term, off, 64);
            act  += __shfl_down(act,  off, 64);
        }
        if (lane == 0) { ls_red[wv] = term; ls_ired[wv] = act; }
        __syncthreads();
        if (t == 0) {
            const double s = (ls_red[0] + ls_red[1]) + (ls_red[2] + ls_red[3]);
            const int    a = ls_ired[0] + ls_ired[1] + ls_ired[2] + ls_ired[3];
            const double sse_tot = atomicAdd(sse_acc, 0.0);
            scal[0] = (float)(sse_tot / 4194304.0);  // commitment_loss
            scal[1] = (float)exp(-s);                // perplexity
            scal[2] = (float)a;                      // active_codes
        }
    }
#undef STAGECHUNK
}

extern "C" void kernel_launch(void* const* d_in, const int* in_sizes, int n_in,
                              void* d_out, int out_size, void* d_ws, size_t ws_size,
                              hipStream_t stream) {
    const float* x      = (const float*)d_in[0];  // [16,64,64,64] fp32
    const float* emb    = (const float*)d_in[1];  // [512,64] fp32
    const float* weight = (const float*)d_in[2];  // [512] fp32

    float* out = (float*)d_out;
    unsigned*       hist     = (unsigned*)d_ws;
    double*         sse      = (double*)((char*)d_ws + 2048);
    unsigned*       done     = (unsigned*)((char*)d_ws + 2056);
    float*          enorm    = (float*)((char*)d_ws + 4096);
    unsigned short* planes_e = (unsigned short*)((char*)d_ws + 8192);

    float* scal    = out + OUT_ELEMS;      // commitment, perplexity, active
    float* idx_out = out + OUT_ELEMS + 3;  // indices as float [65536]

    vq_prep<<<16, 256, 0, stream>>>(emb, planes_e, enorm, hist, sse, done);
    vq_main<<<1024, 256, 0, stream>>>(x, emb, planes_e, enorm, weight, out,
                                      idx_out, hist, sse, done, scal);
}

// Round 8
// 174.330 us; speedup vs baseline: 1.1632x; 1.0060x over previous
//
#include <hip/hip_runtime.h>

// Problem constants
#define HW 4096           // H*W
#define CHW 262144        // C*H*W
#define OUT_ELEMS 4194304 // B*C*H*W
#define FLT_BIG 3.4e38f
#define MST 33            // merge-array row stride (float2): 32 slots + 1 pad

typedef __attribute__((ext_vector_type(8))) short  short8;   // MFMA A/B frag (4 VGPR)
typedef __attribute__((ext_vector_type(4))) float  floatx4;  // MFMA C/D frag
typedef __attribute__((ext_vector_type(4))) int    intx4;

// ws layout:
//   [0,2048)      hist u32[512]
//   [2048,2056)   sse double
//   [2056,2060)   done u32
//   [4096,6144)   enorm f32[512]
//   [8192,139264) planes_frag u16, 128 KB: fragment-major split-bf16 codebook.
//     u16 index = ((((nc*4 + j)*4 + grp)*4 + q)*16 + n)*8 + o
//     code k: nc=k>>6, grp=(k&63)>>4, n=k&15; element e in [0,128) of
//     [eh(64)|el(64)]: j=e>>5, q=(e&31)>>3, o=e&7.
//     => wave lane (col=n, quad=q) loads 16 B at block_base + lane*16:
//        one fully-coalesced 1 KB dwordx4 per B-fragment. No LDS staging.

__device__ __forceinline__ unsigned bf16_rne(float f) {
    unsigned u = __float_as_uint(f);
    return (u + 0x7FFFu + ((u >> 16) & 1u)) >> 16;  // RNE bf16 bits
}

__device__ __forceinline__ void split8(const float* f, intx4* hi, intx4* lo) {
    unsigned h[4], l[4];
#pragma unroll
    for (int j = 0; j < 4; ++j) {
        const unsigned h0 = bf16_rne(f[2 * j]);
        const unsigned h1 = bf16_rne(f[2 * j + 1]);
        const float hf0 = __uint_as_float(h0 << 16);
        const float hf1 = __uint_as_float(h1 << 16);
        const unsigned l0 = bf16_rne(f[2 * j] - hf0);
        const unsigned l1 = bf16_rne(f[2 * j + 1] - hf1);
        h[j] = h0 | (h1 << 16);
        l[j] = l0 | (l1 << 16);
    }
    *hi = intx4{(int)h[0], (int)h[1], (int)h[2], (int)h[3]};
    *lo = intx4{(int)l[0], (int)l[1], (int)l[2], (int)l[3]};
}

// prep: 16 blocks x 256 threads; 32 codes/block. Scattered u16 writes are fine
// here (one-shot ~128 KB). Block 0 zeroes hist/sse/done.
__global__ void vq_prep(const float* __restrict__ emb,
                        unsigned short* __restrict__ pfrag,
                        float* __restrict__ enorm,
                        unsigned* __restrict__ hist,
                        double* __restrict__ sse,
                        unsigned* __restrict__ done) {
    const int t = threadIdx.x;
    const int lane = t & 63;
    if (blockIdx.x == 0) {
        hist[t] = 0u; hist[t + 256] = 0u;
        if (t == 0) { *sse = 0.0; *done = 0u; }
    }
#pragma unroll
    for (int i = 0; i < 8; ++i) {
        const int f    = (i << 8) + t;
        const int code = (blockIdx.x << 5) + (f >> 6);  // wave-uniform
        const int c    = lane;
        const float v  = emb[(code << 6) + c];          // 256B coalesced
        const unsigned hb = bf16_rne(v);
        const float hf    = __uint_as_float(hb << 16);
        const unsigned lb = bf16_rne(v - hf);
        const int nc = code >> 6, grp = (code & 63) >> 4, n = code & 15;
        const int q = (c & 31) >> 3, o = c & 7;
        const int jh = c >> 5;        // eh element e=c
        const int jl = 2 + (c >> 5);  // el element e=64+c
        pfrag[((((size_t)(nc*4 + jh)*4 + grp)*4 + q)*16 + n)*8 + o] = (unsigned short)hb;
        pfrag[((((size_t)(nc*4 + jl)*4 + grp)*4 + q)*16 + n)*8 + o] = (unsigned short)lb;
        float s = v * v;
#pragma unroll
        for (int off = 32; off > 0; off >>= 1) s += __shfl_xor(s, off, 64);
        if (lane == 0) enorm[code] = s;
    }
}

// Main: 1024 blocks x 256 threads; 64 rows/block (one (b,h) stripe, row = w).
// Wave wv: rows [32*(wv>>1), +32), code-half (wv&1) of each 64-code chunk.
// ZERO barriers in the K-loop: B-fragments are MFMA'd directly from L2 via
// coalesced 1 KB loads of the fragment-major codebook (R7 lesson: the
// barrier-per-chunk staging loop convoyed the whole CU at ~110 us regardless
// of staging quality).
__global__ __launch_bounds__(256)
void vq_main(const float* __restrict__ x_in, const float* __restrict__ emb,
             const unsigned short* __restrict__ pfrag,
             const float* __restrict__ enorm, const float* __restrict__ weight,
             float* __restrict__ out, float* __restrict__ idx_out,
             unsigned* __restrict__ hist, double* __restrict__ sse_acc,
             unsigned* __restrict__ done, float* __restrict__ scal) {
    __shared__ float2 m1[64 * MST];   // (d, idx-bits) list-1, slot = khalf*16+col
    __shared__ float2 m2[64 * MST];   // list-2
    __shared__ int    qidx[64];
    __shared__ double ls_red[4];
    __shared__ int    ls_ired[4];
    __shared__ int    ls_flag;

    const int t     = threadIdx.x;
    const int lane  = t & 63;
    const int wv    = t >> 6;
    const int col   = lane & 15;
    const int quad  = lane >> 4;
    const int blk   = blockIdx.x;
    const int mrow0 = (wv >> 1) << 5;   // wave row base (0/32)
    const int khalf = wv & 1;           // code-half of each 64-chunk
    const int ncol0 = khalf << 5;
    const int b = blk >> 6, h = blk & 63;
    const float* xb = x_in + (size_t)b * CHW + h * 64;

    // ---- A-frags: 16 x-values per Mt, direct from BCHW global (coalesced),
    // split to bf16 hi/lo, register-resident for the whole kernel ----
    short8 Ah[2][2], Al[2][2];
#pragma unroll
    for (int m = 0; m < 2; ++m) {
        const int w = mrow0 + (m << 4) + col;
#pragma unroll
        for (int u = 0; u < 2; ++u) {
            float f[8];
#pragma unroll
            for (int j = 0; j < 8; ++j) {
                const int c = (u << 5) + (quad << 3) + j;
                f[j] = xb[(size_t)c * HW + w];
            }
            intx4 hi, lo;
            split8(f, &hi, &lo);
            Ah[m][u] = __builtin_bit_cast(short8, hi);
            Al[m][u] = __builtin_bit_cast(short8, lo);
        }
    }

    float B1[8], B2[8]; int I1[8], I2[8];
#pragma unroll
    for (int s = 0; s < 8; ++s) { B1[s] = FLT_BIG; B2[s] = FLT_BIG; I1[s] = 0x3FFFFFFF; I2[s] = 0x3FFFFFFF; }

    // fragment base for this lane: + j*4096 + g*1024 within each 16 KB chunk
    const char* pf = (const char*)pfrag + (size_t)lane * 16 + ((size_t)khalf << 11);

#pragma unroll 1
    for (int nc = 0; nc < 8; ++nc) {
        const char* base = pf + ((size_t)nc << 14);
        const int K0 = nc << 6;
        const float en0 = enorm[K0 + ncol0 + col];
        const float en1 = enorm[K0 + ncol0 + 16 + col];

        floatx4 a00{0.f,0.f,0.f,0.f}, a01{0.f,0.f,0.f,0.f};
        floatx4 a10{0.f,0.f,0.f,0.f}, a11{0.f,0.f,0.f,0.f};
#define BLD(j, g) (*(const short8*)(base + ((j) << 12) + ((g) << 10)))
        {   // j=0: eh c[0,32) -> pairs with Ah[.][0] and Al[.][0]
            const short8 b0 = BLD(0, 0), b1 = BLD(0, 1);
            a00 = __builtin_amdgcn_mfma_f32_16x16x32_bf16(Ah[0][0], b0, a00, 0, 0, 0);
            a01 = __builtin_amdgcn_mfma_f32_16x16x32_bf16(Ah[0][0], b1, a01, 0, 0, 0);
            a10 = __builtin_amdgcn_mfma_f32_16x16x32_bf16(Ah[1][0], b0, a10, 0, 0, 0);
            a11 = __builtin_amdgcn_mfma_f32_16x16x32_bf16(Ah[1][0], b1, a11, 0, 0, 0);
            a00 = __builtin_amdgcn_mfma_f32_16x16x32_bf16(Al[0][0], b0, a00, 0, 0, 0);
            a01 = __builtin_amdgcn_mfma_f32_16x16x32_bf16(Al[0][0], b1, a01, 0, 0, 0);
            a10 = __builtin_amdgcn_mfma_f32_16x16x32_bf16(Al[1][0], b0, a10, 0, 0, 0);
            a11 = __builtin_amdgcn_mfma_f32_16x16x32_bf16(Al[1][0], b1, a11, 0, 0, 0);
        }
        {   // j=1: eh c[32,64) -> Ah[.][1], Al[.][1]
            const short8 b0 = BLD(1, 0), b1 = BLD(1, 1);
            a00 = __builtin_amdgcn_mfma_f32_16x16x32_bf16(Ah[0][1], b0, a00, 0, 0, 0);
            a01 = __builtin_amdgcn_mfma_f32_16x16x32_bf16(Ah[0][1], b1, a01, 0, 0, 0);
            a10 = __builtin_amdgcn_mfma_f32_16x16x32_bf16(Ah[1][1], b0, a10, 0, 0, 0);
            a11 = __builtin_amdgcn_mfma_f32_16x16x32_bf16(Ah[1][1], b1, a11, 0, 0, 0);
            a00 = __builtin_amdgcn_mfma_f32_16x16x32_bf16(Al[0][1], b0, a00, 0, 0, 0);
            a01 = __builtin_amdgcn_mfma_f32_16x16x32_bf16(Al[0][1], b1, a01, 0, 0, 0);
            a10 = __builtin_amdgcn_mfma_f32_16x16x32_bf16(Al[1][1], b0, a10, 0, 0, 0);
            a11 = __builtin_amdgcn_mfma_f32_16x16x32_bf16(Al[1][1], b1, a11, 0, 0, 0);
        }
        {   // j=2: el c[0,32) -> Ah[.][0] only
            const short8 b0 = BLD(2, 0), b1 = BLD(2, 1);
            a00 = __builtin_amdgcn_mfma_f32_16x16x32_bf16(Ah[0][0], b0, a00, 0, 0, 0);
            a01 = __builtin_amdgcn_mfma_f32_16x16x32_bf16(Ah[0][0], b1, a01, 0, 0, 0);
            a10 = __builtin_amdgcn_mfma_f32_16x16x32_bf16(Ah[1][0], b0, a10, 0, 0, 0);
            a11 = __builtin_amdgcn_mfma_f32_16x16x32_bf16(Ah[1][0], b1, a11, 0, 0, 0);
        }
        {   // j=3: el c[32,64) -> Ah[.][1] only
            const short8 b0 = BLD(3, 0), b1 = BLD(3, 1);
            a00 = __builtin_amdgcn_mfma_f32_16x16x32_bf16(Ah[0][1], b0, a00, 0, 0, 0);
            a01 = __builtin_amdgcn_mfma_f32_16x16x32_bf16(Ah[0][1], b1, a01, 0, 0, 0);
            a10 = __builtin_amdgcn_mfma_f32_16x16x32_bf16(Ah[1][1], b0, a10, 0, 0, 0);
            a11 = __builtin_amdgcn_mfma_f32_16x16x32_bf16(Ah[1][1], b1, a11, 0, 0, 0);
        }
#undef BLD

        // top-2 update; codes ascend (nt inner, nc outer) -> strict < keeps
        // first occurrence within this wave's code subset.
#pragma unroll
        for (int nt = 0; nt < 2; ++nt) {
            const int code = K0 + ncol0 + (nt << 4) + col;
            const float en = nt ? en1 : en0;
#pragma unroll
            for (int m = 0; m < 2; ++m) {
                const floatx4 av = nt ? (m ? a11 : a01) : (m ? a10 : a00);
#pragma unroll
                for (int reg = 0; reg < 4; ++reg) {
                    const float d = fmaf(-2.f, av[reg], en);
                    const int s = (m << 2) + reg;
                    if (d < B1[s])      { B2[s] = B1[s]; I2[s] = I1[s]; B1[s] = d; I1[s] = code; }
                    else if (d < B2[s]) { B2[s] = d; I2[s] = code; }
                }
            }
        }
    }

    // ---- publish per (row, khalf*16+col) slot; disjoint writers, no race ----
#pragma unroll
    for (int s = 0; s < 8; ++s) {
        const int row  = mrow0 + ((s >> 2) << 4) + (quad << 2) + (s & 3);
        const int slot = row * MST + (khalf << 4) + col;
        m1[slot] = make_float2(B1[s], __int_as_float(I1[s]));
        m2[slot] = make_float2(B2[s], __int_as_float(I2[s]));
    }
    __syncthreads();

    // ---- per-row finalize: scan 32 disjoint top-2 lists, fp64 rescue ----
    if (t < 64) {
        const int r = t;
        const float* xp = xb + r;
        float b1 = FLT_BIG, b2 = FLT_BIG; int i1 = 0x3FFFFFFF, i2 = 0x3FFFFFFF;
        for (int m = 0; m < 32; ++m) {
            const float2 c1v = m1[r * MST + m];
            const float2 c2v = m2[r * MST + m];
            const float c1 = c1v.x; const int j1 = __float_as_int(c1v.y);
            const float c2 = c2v.x; const int j2 = __float_as_int(c2v.y);
            if (c1 < b1 || (c1 == b1 && j1 < i1))      { b2 = b1; i2 = i1; b1 = c1; i1 = j1; }
            else if (c1 < b2 || (c1 == b2 && j1 < i2)) { b2 = c1; i2 = j1; }
            if (c2 < b2 || (c2 == b2 && j2 < i2))      { b2 = c2; i2 = j2; }
        }
        if (b2 - b1 < 1e-2f) {   // split-bf16 noise ~2e-4; rescue near-ties exactly
            const float* e1p = emb + ((size_t)i1 << 6);
            const float* e2p = emb + ((size_t)i2 << 6);
            double d1 = 0.0, d2 = 0.0;
            for (int c = 0; c < 64; ++c) {
                const double xv = (double)xp[(size_t)c * HW];
                const double t1 = xv - (double)e1p[c];
                const double t2 = xv - (double)e2p[c];
                d1 = fma(t1, t1, d1);
                d2 = fma(t2, t2, d2);
            }
            if (d2 < d1 || (d2 == d1 && i2 < i1)) i1 = i2;
        }
        qidx[r] = i1;
        atomicAdd(&hist[i1], 1u);
        idx_out[(blk << 6) + r] = (float)i1;
    }
    __syncthreads();

    // ---- epilogue: quantized out (coalesced along w) + SSE (f32 local,
    // f64 block atomic) ----
    {
        const int r  = lane;            // row
        const int c0 = wv << 4;         // 16 channels per wave
        const float* xp = xb + r;
        float*       op = out + (size_t)b * CHW + h * 64 + r;
        const float* eq = emb + ((size_t)qidx[r] << 6);
        float sse_local = 0.f;
#pragma unroll
        for (int cc = 0; cc < 16; ++cc) {
            const int c = c0 + cc;
            const float qc = eq[c];
            const float dx = qc - xp[(size_t)c * HW];
            sse_local = fmaf(dx, dx, sse_local);
            op[(size_t)c * HW] = qc;
        }
#pragma unroll
        for (int off = 32; off > 0; off >>= 1)
            sse_local += __shfl_down(sse_local, off, 64);
        if (lane == 0) ls_red[wv] = (double)sse_local;
        __syncthreads();
        if (t == 0)
            atomicAdd(sse_acc, (ls_red[0] + ls_red[1]) + (ls_red[2] + ls_red[3]));
    }

    // ---- last block computes the scalars ----
    if (t == 0) {
        __threadfence();
        const unsigned old = atomicAdd(done, 1u);
        ls_flag = (old == gridDim.x - 1) ? 1 : 0;
    }
    __syncthreads();
    if (ls_flag) {
        __threadfence();
        double term = 0.0; int act = 0;
#pragma unroll
        for (int j = 0; j < 2; ++j) {
            const int k = t + (j << 8);
            const unsigned cnt = atomicAdd(&hist[k], 0u);  // coherent read
            const double p = (double)cnt / 65536.0;
            term += p * log(p + 1e-10);
            act  += (weight[k] >= 0.01f) ? 1 : 0;
        }
#pragma unroll
        for (int off = 32; off > 0; off >>= 1) {
            term += __shfl_down(term, off, 64);
            act  += __shfl_down(act,  off, 64);
        }
        if (lane == 0) { ls_red[wv] = term; ls_ired[wv] = act; }
        __syncthreads();
        if (t == 0) {
            const double s = (ls_red[0] + ls_red[1]) + (ls_red[2] + ls_red[3]);
            const int    a = ls_ired[0] + ls_ired[1] + ls_ired[2] + ls_ired[3];
            const double sse_tot = atomicAdd(sse_acc, 0.0);
            scal[0] = (float)(sse_tot / 4194304.0);  // commitment_loss
            scal[1] = (float)exp(-s);                // perplexity
            scal[2] = (float)a;                      // active_codes
        }
    }
}

extern "C" void kernel_launch(void* const* d_in, const int* in_sizes, int n_in,
                              void* d_out, int out_size, void* d_ws, size_t ws_size,
                              hipStream_t stream) {
    const float* x      = (const float*)d_in[0];  // [16,64,64,64] fp32
    const float* emb    = (const float*)d_in[1];  // [512,64] fp32
    const float* weight = (const float*)d_in[2];  // [512] fp32

    float* out = (float*)d_out;
    unsigned*       hist  = (unsigned*)d_ws;
    double*         sse   = (double*)((char*)d_ws + 2048);
    unsigned*       done  = (unsigned*)((char*)d_ws + 2056);
    float*          enorm = (float*)((char*)d_ws + 4096);
    unsigned short* pfrag = (unsigned short*)((char*)d_ws + 8192);

    float* scal    = out + OUT_ELEMS;      // commitment, perplexity, active
    float* idx_out = out + OUT_ELEMS + 3;  // indices as float [65536]

    vq_prep<<<16, 256, 0, stream>>>(emb, pfrag, enorm, hist, sse, done);
    vq_main<<<1024, 256, 0, stream>>>(x, emb, pfrag, enorm, weight, out,
                                      idx_out, hist, sse, done, scal);
}

// Round 9
// 141.625 us; speedup vs baseline: 1.4319x; 1.2309x over previous
//
#include <hip/hip_runtime.h>

// Problem constants
#define HW 4096           // H*W
#define CHW 262144        // C*H*W
#define OUT_ELEMS 4194304 // B*C*H*W
#define FLT_BIG 3.4e38f

typedef __attribute__((ext_vector_type(8))) short  short8;   // MFMA A/B frag (4 VGPR)
typedef __attribute__((ext_vector_type(4))) float  floatx4;  // MFMA C/D frag
typedef __attribute__((ext_vector_type(4))) int    intx4;

// ws layout (no zero-init needed -- every byte read is written first):
//   [4096,6144)     enorm f32[512]
//   [8192,139264)   planes_frag u16 (128 KB, fragment-major split-bf16 codebook)
//   [139264,147456) ws_sse double[1024]  (per-block SSE, plain stores)
//   [147456,212992) part u32[32][512]    (per-hist-block partial histograms)

__device__ __forceinline__ unsigned bf16_rne(float f) {
    unsigned u = __float_as_uint(f);
    return (u + 0x7FFFu + ((u >> 16) & 1u)) >> 16;  // RNE bf16 bits
}

__device__ __forceinline__ void split8(const float* f, intx4* hi, intx4* lo) {
    unsigned h[4], l[4];
#pragma unroll
    for (int j = 0; j < 4; ++j) {
        const unsigned h0 = bf16_rne(f[2 * j]);
        const unsigned h1 = bf16_rne(f[2 * j + 1]);
        const float hf0 = __uint_as_float(h0 << 16);
        const float hf1 = __uint_as_float(h1 << 16);
        const unsigned l0 = bf16_rne(f[2 * j] - hf0);
        const unsigned l1 = bf16_rne(f[2 * j + 1] - hf1);
        h[j] = h0 | (h1 << 16);
        l[j] = l0 | (l1 << 16);
    }
    *hi = intx4{(int)h[0], (int)h[1], (int)h[2], (int)h[3]};
    *lo = intx4{(int)l[0], (int)l[1], (int)l[2], (int)l[3]};
}

// prep: 16 blocks x 256 threads; 32 codes/block. Fragment-major split-bf16
// codebook + exact fp32 enorm. (Same as R8 minus the ws zeroing.)
__global__ void vq_prep(const float* __restrict__ emb,
                        unsigned short* __restrict__ pfrag,
                        float* __restrict__ enorm) {
    const int t = threadIdx.x;
    const int lane = t & 63;
#pragma unroll
    for (int i = 0; i < 8; ++i) {
        const int f    = (i << 8) + t;
        const int code = (blockIdx.x << 5) + (f >> 6);  // wave-uniform
        const int c    = lane;
        const float v  = emb[(code << 6) + c];          // 256B coalesced
        const unsigned hb = bf16_rne(v);
        const float hf    = __uint_as_float(hb << 16);
        const unsigned lb = bf16_rne(v - hf);
        const int nc = code >> 6, grp = (code & 63) >> 4, n = code & 15;
        const int q = (c & 31) >> 3, o = c & 7;
        const int jh = c >> 5;        // eh element e=c
        const int jl = 2 + (c >> 5);  // el element e=64+c
        pfrag[((((size_t)(nc*4 + jh)*4 + grp)*4 + q)*16 + n)*8 + o] = (unsigned short)hb;
        pfrag[((((size_t)(nc*4 + jl)*4 + grp)*4 + q)*16 + n)*8 + o] = (unsigned short)lb;
        float s = v * v;
#pragma unroll
        for (int off = 32; off > 0; off >>= 1) s += __shfl_xor(s, off, 64);
        if (lane == 0) enorm[code] = s;
    }
}

// Main: 1024 blocks x 256 threads; 64 rows/block (one (b,h) stripe, row = w).
// K-loop byte-identical to R8 (zero barriers, L2-direct fragment loads).
// R9 changes: NO global atomics anywhere (hist -> separate kernels; SSE ->
// plain per-block store); merge via shfl butterfly -> LDS ~3.4 KB (6 blk/CU).
__global__ __launch_bounds__(256)
void vq_main(const float* __restrict__ x_in, const float* __restrict__ emb,
             const unsigned short* __restrict__ pfrag,
             const float* __restrict__ enorm,
             float* __restrict__ out, float* __restrict__ idx_out,
             double* __restrict__ ws_sse) {
    __shared__ float  b1s[2][64], b2s[2][64];
    __shared__ int    i1s[2][64], i2s[2][64], qidx[64];
    __shared__ double ls_red[4];

    const int t     = threadIdx.x;
    const int lane  = t & 63;
    const int wv    = t >> 6;
    const int col   = lane & 15;
    const int quad  = lane >> 4;
    const int blk   = blockIdx.x;
    const int mrow0 = (wv >> 1) << 5;   // wave row base (0/32)
    const int khalf = wv & 1;           // code-half of each 64-chunk
    const int ncol0 = khalf << 5;
    const int b = blk >> 6, h = blk & 63;
    const float* xb = x_in + (size_t)b * CHW + h * 64;

    // ---- A-frags: direct from BCHW global, split-bf16, register-resident ----
    short8 Ah[2][2], Al[2][2];
#pragma unroll
    for (int m = 0; m < 2; ++m) {
        const int w = mrow0 + (m << 4) + col;
#pragma unroll
        for (int u = 0; u < 2; ++u) {
            float f[8];
#pragma unroll
            for (int j = 0; j < 8; ++j) {
                const int c = (u << 5) + (quad << 3) + j;
                f[j] = xb[(size_t)c * HW + w];
            }
            intx4 hi, lo;
            split8(f, &hi, &lo);
            Ah[m][u] = __builtin_bit_cast(short8, hi);
            Al[m][u] = __builtin_bit_cast(short8, lo);
        }
    }

    float B1[8], B2[8]; int I1[8], I2[8];
#pragma unroll
    for (int s = 0; s < 8; ++s) { B1[s] = FLT_BIG; B2[s] = FLT_BIG; I1[s] = 0x3FFFFFFF; I2[s] = 0x3FFFFFFF; }

    const char* pf = (const char*)pfrag + (size_t)lane * 16 + ((size_t)khalf << 11);

#pragma unroll 1
    for (int nc = 0; nc < 8; ++nc) {
        const char* base = pf + ((size_t)nc << 14);
        const int K0 = nc << 6;
        const float en0 = enorm[K0 + ncol0 + col];
        const float en1 = enorm[K0 + ncol0 + 16 + col];

        floatx4 a00{0.f,0.f,0.f,0.f}, a01{0.f,0.f,0.f,0.f};
        floatx4 a10{0.f,0.f,0.f,0.f}, a11{0.f,0.f,0.f,0.f};
#define BLD(j, g) (*(const short8*)(base + ((j) << 12) + ((g) << 10)))
        {   // j=0: eh c[0,32)
            const short8 b0 = BLD(0, 0), b1 = BLD(0, 1);
            a00 = __builtin_amdgcn_mfma_f32_16x16x32_bf16(Ah[0][0], b0, a00, 0, 0, 0);
            a01 = __builtin_amdgcn_mfma_f32_16x16x32_bf16(Ah[0][0], b1, a01, 0, 0, 0);
            a10 = __builtin_amdgcn_mfma_f32_16x16x32_bf16(Ah[1][0], b0, a10, 0, 0, 0);
            a11 = __builtin_amdgcn_mfma_f32_16x16x32_bf16(Ah[1][0], b1, a11, 0, 0, 0);
            a00 = __builtin_amdgcn_mfma_f32_16x16x32_bf16(Al[0][0], b0, a00, 0, 0, 0);
            a01 = __builtin_amdgcn_mfma_f32_16x16x32_bf16(Al[0][0], b1, a01, 0, 0, 0);
            a10 = __builtin_amdgcn_mfma_f32_16x16x32_bf16(Al[1][0], b0, a10, 0, 0, 0);
            a11 = __builtin_amdgcn_mfma_f32_16x16x32_bf16(Al[1][0], b1, a11, 0, 0, 0);
        }
        {   // j=1: eh c[32,64)
            const short8 b0 = BLD(1, 0), b1 = BLD(1, 1);
            a00 = __builtin_amdgcn_mfma_f32_16x16x32_bf16(Ah[0][1], b0, a00, 0, 0, 0);
            a01 = __builtin_amdgcn_mfma_f32_16x16x32_bf16(Ah[0][1], b1, a01, 0, 0, 0);
            a10 = __builtin_amdgcn_mfma_f32_16x16x32_bf16(Ah[1][1], b0, a10, 0, 0, 0);
            a11 = __builtin_amdgcn_mfma_f32_16x16x32_bf16(Ah[1][1], b1, a11, 0, 0, 0);
            a00 = __builtin_amdgcn_mfma_f32_16x16x32_bf16(Al[0][1], b0, a00, 0, 0, 0);
            a01 = __builtin_amdgcn_mfma_f32_16x16x32_bf16(Al[0][1], b1, a01, 0, 0, 0);
            a10 = __builtin_amdgcn_mfma_f32_16x16x32_bf16(Al[1][1], b0, a10, 0, 0, 0);
            a11 = __builtin_amdgcn_mfma_f32_16x16x32_bf16(Al[1][1], b1, a11, 0, 0, 0);
        }
        {   // j=2: el c[0,32)
            const short8 b0 = BLD(2, 0), b1 = BLD(2, 1);
            a00 = __builtin_amdgcn_mfma_f32_16x16x32_bf16(Ah[0][0], b0, a00, 0, 0, 0);
            a01 = __builtin_amdgcn_mfma_f32_16x16x32_bf16(Ah[0][0], b1, a01, 0, 0, 0);
            a10 = __builtin_amdgcn_mfma_f32_16x16x32_bf16(Ah[1][0], b0, a10, 0, 0, 0);
            a11 = __builtin_amdgcn_mfma_f32_16x16x32_bf16(Ah[1][0], b1, a11, 0, 0, 0);
        }
        {   // j=3: el c[32,64)
            const short8 b0 = BLD(3, 0), b1 = BLD(3, 1);
            a00 = __builtin_amdgcn_mfma_f32_16x16x32_bf16(Ah[0][1], b0, a00, 0, 0, 0);
            a01 = __builtin_amdgcn_mfma_f32_16x16x32_bf16(Ah[0][1], b1, a01, 0, 0, 0);
            a10 = __builtin_amdgcn_mfma_f32_16x16x32_bf16(Ah[1][1], b0, a10, 0, 0, 0);
            a11 = __builtin_amdgcn_mfma_f32_16x16x32_bf16(Ah[1][1], b1, a11, 0, 0, 0);
        }
#undef BLD

#pragma unroll
        for (int nt = 0; nt < 2; ++nt) {
            const int code = K0 + ncol0 + (nt << 4) + col;
            const float en = nt ? en1 : en0;
#pragma unroll
            for (int m = 0; m < 2; ++m) {
                const floatx4 av = nt ? (m ? a11 : a01) : (m ? a10 : a00);
#pragma unroll
                for (int reg = 0; reg < 4; ++reg) {
                    const float d = fmaf(-2.f, av[reg], en);
                    const int s = (m << 2) + reg;
                    if (d < B1[s])      { B2[s] = B1[s]; I2[s] = I1[s]; B1[s] = d; I1[s] = code; }
                    else if (d < B2[s]) { B2[s] = d; I2[s] = code; }
                }
            }
        }
    }

    // ---- cross-lane top-2 butterfly over col bits (R7-verified; disjoint
    // code sets per lane, explicit index tie-break = first-occurrence) ----
#pragma unroll
    for (int off = 1; off <= 8; off <<= 1) {
#pragma unroll
        for (int s = 0; s < 8; ++s) {
            const float ob1 = __shfl_xor(B1[s], off, 64);
            const int   oi1 = __shfl_xor(I1[s], off, 64);
            const float ob2 = __shfl_xor(B2[s], off, 64);
            const int   oi2 = __shfl_xor(I2[s], off, 64);
            if (ob1 < B1[s] || (ob1 == B1[s] && oi1 < I1[s])) {
                float nb2; int ni2;
                if (B1[s] < ob2 || (B1[s] == ob2 && I1[s] < oi2)) { nb2 = B1[s]; ni2 = I1[s]; }
                else                                              { nb2 = ob2;  ni2 = oi2; }
                B1[s] = ob1; I1[s] = oi1; B2[s] = nb2; I2[s] = ni2;
            } else if (ob1 < B2[s] || (ob1 == B2[s] && oi1 < I2[s])) {
                B2[s] = ob1; I2[s] = oi1;
            }
        }
    }
    if (col == 0) {
#pragma unroll
        for (int s = 0; s < 8; ++s) {
            const int row = mrow0 + ((s >> 2) << 4) + (quad << 2) + (s & 3);
            b1s[khalf][row] = B1[s]; b2s[khalf][row] = B2[s];
            i1s[khalf][row] = I1[s]; i2s[khalf][row] = I2[s];
        }
    }
    __syncthreads();

    // ---- per-row finalize: merge halves, fp64 rescue on near-ties, idx out
    // (NO hist atomic -- histogram built later from idx_out) ----
    if (t < 64) {
        const int r = t;
        const float* xp = xb + r;
        float b1 = b1s[0][r], b2 = b2s[0][r];
        int   i1 = i1s[0][r], i2 = i2s[0][r];
        {
            const float c1 = b1s[1][r]; const int j1 = i1s[1][r];
            const float c2 = b2s[1][r]; const int j2 = i2s[1][r];
            if (c1 < b1 || (c1 == b1 && j1 < i1))      { b2 = b1; i2 = i1; b1 = c1; i1 = j1; }
            else if (c1 < b2 || (c1 == b2 && j1 < i2)) { b2 = c1; i2 = j1; }
            if (c2 < b2 || (c2 == b2 && j2 < i2))      { b2 = c2; i2 = j2; }
        }
        if (b2 - b1 < 1e-2f) {   // split-bf16 noise ~2e-4; rescue near-ties exactly
            const float* e1p = emb + ((size_t)i1 << 6);
            const float* e2p = emb + ((size_t)i2 << 6);
            double d1 = 0.0, d2 = 0.0;
            for (int c = 0; c < 64; ++c) {
                const double xv = (double)xp[(size_t)c * HW];
                const double t1 = xv - (double)e1p[c];
                const double t2 = xv - (double)e2p[c];
                d1 = fma(t1, t1, d1);
                d2 = fma(t2, t2, d2);
            }
            if (d2 < d1 || (d2 == d1 && i2 < i1)) i1 = i2;
        }
        qidx[r] = i1;
        idx_out[(blk << 6) + r] = (float)i1;
    }
    __syncthreads();

    // ---- epilogue: quantized out (coalesced along w) + per-block SSE ----
    {
        const int r  = lane;
        const int c0 = wv << 4;
        const float* xp = xb + r;
        float*       op = out + (size_t)b * CHW + h * 64 + r;
        const float* eq = emb + ((size_t)qidx[r] << 6);
        float sse_local = 0.f;
#pragma unroll
        for (int cc = 0; cc < 16; ++cc) {
            const int c = c0 + cc;
            const float qc = eq[c];
            const float dx = qc - xp[(size_t)c * HW];
            sse_local = fmaf(dx, dx, sse_local);
            op[(size_t)c * HW] = qc;
        }
#pragma unroll
        for (int off = 32; off > 0; off >>= 1)
            sse_local += __shfl_down(sse_local, off, 64);
        if (lane == 0) ls_red[wv] = (double)sse_local;
        __syncthreads();
        if (t == 0)
            ws_sse[blk] = (ls_red[0] + ls_red[1]) + (ls_red[2] + ls_red[3]);  // plain store
    }
}

// hist: 32 blocks x 256 threads; each block LDS-histograms 2048 indices from
// idx_out and writes a non-atomic partial histogram. Kernel-boundary ordering
// provides coherence (no device atomics, no fences).
__global__ void vq_hist(const float* __restrict__ idx_out,
                        unsigned* __restrict__ part) {
    __shared__ unsigned hs[512];
    const int t = threadIdx.x;
    hs[t] = 0u; hs[t + 256] = 0u;
    __syncthreads();
    const float4* ip = (const float4*)(idx_out + (blockIdx.x << 11));
#pragma unroll
    for (int i = 0; i < 2; ++i) {
        const float4 v = ip[(i << 8) + t];    // coalesced
        atomicAdd(&hs[(int)v.x], 1u);         // LDS atomics (fast, low contention)
        atomicAdd(&hs[(int)v.y], 1u);
        atomicAdd(&hs[(int)v.z], 1u);
        atomicAdd(&hs[(int)v.w], 1u);
    }
    __syncthreads();
    unsigned* pp = part + (blockIdx.x << 9);
    pp[t] = hs[t]; pp[t + 256] = hs[t + 256];  // coalesced plain stores
}

// scal: 1 block x 512 threads. Reduces partial hists -> perplexity, sums
// per-block SSE -> commitment, counts active codes. Writes the 3 scalars.
__global__ void vq_scal(const unsigned* __restrict__ part,
                        const double* __restrict__ ws_sse,
                        const float* __restrict__ weight,
                        float* __restrict__ scal) {
    __shared__ double redt[8], reds[8];
    __shared__ int    redi[8];
    const int k = threadIdx.x;       // 0..511 = code
    const int lane = k & 63, wv = k >> 6;
    unsigned cnt = 0;
#pragma unroll
    for (int p = 0; p < 32; ++p) cnt += part[(p << 9) + k];   // coalesced per p
    const double pr = (double)cnt / 65536.0;
    double term = pr * log(pr + 1e-10);
    double ssep = ws_sse[k] + ws_sse[k + 512];
    int act = (weight[k] >= 0.01f) ? 1 : 0;
#pragma unroll
    for (int off = 32; off > 0; off >>= 1) {
        term += __shfl_down(term, off, 64);
        ssep += __shfl_down(ssep, off, 64);
        act  += __shfl_down(act,  off, 64);
    }
    if (lane == 0) { redt[wv] = term; reds[wv] = ssep; redi[wv] = act; }
    __syncthreads();
    if (k == 0) {
        double s = 0.0, ss = 0.0; int a = 0;
#pragma unroll
        for (int i = 0; i < 8; ++i) { s += redt[i]; ss += reds[i]; a += redi[i]; }
        scal[0] = (float)(ss / 4194304.0);  // commitment_loss
        scal[1] = (float)exp(-s);           // perplexity
        scal[2] = (float)a;                 // active_codes
    }
}

extern "C" void kernel_launch(void* const* d_in, const int* in_sizes, int n_in,
                              void* d_out, int out_size, void* d_ws, size_t ws_size,
                              hipStream_t stream) {
    const float* x      = (const float*)d_in[0];  // [16,64,64,64] fp32
    const float* emb    = (const float*)d_in[1];  // [512,64] fp32
    const float* weight = (const float*)d_in[2];  // [512] fp32

    float* out = (float*)d_out;
    float*          enorm  = (float*)((char*)d_ws + 4096);
    unsigned short* pfrag  = (unsigned short*)((char*)d_ws + 8192);
    double*         ws_sse = (double*)((char*)d_ws + 139264);
    unsigned*       part   = (unsigned*)((char*)d_ws + 147456);

    float* scal    = out + OUT_ELEMS;      // commitment, perplexity, active
    float* idx_out = out + OUT_ELEMS + 3;  // indices as float [65536]

    vq_prep<<<16, 256, 0, stream>>>(emb, pfrag, enorm);
    vq_main<<<1024, 256, 0, stream>>>(x, emb, pfrag, enorm, out, idx_out, ws_sse);
    vq_hist<<<32, 256, 0, stream>>>(idx_out, part);
    vq_scal<<<1, 512, 0, stream>>>(part, ws_sse, weight, scal);
}